// Round 12
// baseline (133.717 us; speedup 1.0000x reference)
//
#include <hip/hip_runtime.h>

#define PH 7
#define PW 7
#define BINS (PH * PW)   // 49

__device__ __forceinline__ float4 max4(float4 a, float4 b) {
    float4 r;
    r.x = fmaxf(a.x, b.x); r.y = fmaxf(a.y, b.y);
    r.z = fmaxf(a.z, b.z); r.w = fmaxf(a.w, b.w);
    return r;
}

// One block = 128 threads = 2 waves = ONE output bin (b, n, h, w).
// The two waves split the bin's columns interleaved (wave wv owns columns
// xs+wv, xs+wv+2, ...): identical work per wave (+-1 column) -> zero
// imbalance, block retires as one. Doubles the 64-thr workgroup-slot
// residency cap (16 -> 32 waves/CU). Cross-wave merge: 1KB LDS, 1 barrier.
// Lane t: row-in-pair pp = t>>5, channels c0 = (t&31)*4 (C == 128); each
// 1KB wave-load covers 2 adjacent y-rows. Raggedness is wave-uniform
// (H, W uniform per bin): pair remainder by branch, odd-H via broadcast
// same-address row loads (idempotent under max), odd column count via solo
// column tail. Main body: 2 owned columns x 2 pair-loads = 4 loads in flight.
// Grid: (id & 7) == b pins image b to XCD b (L2 locality; FETCH 213->86 MB).
__global__ __launch_bounds__(128) void roi_maxpool_kernel(
    const float* __restrict__ feat,   // [B, 128, 128, 128]
    const int*   __restrict__ rois,   // [B, N, 4] = (minX, minY, maxX, maxY)
    float*       __restrict__ out,    // [B, N, PH, PW, 128]
    int N, int xcd_swizzle)
{
    const int Y = 128, C = 128;

    const int id = blockIdx.x;
    int b, rest;
    if (xcd_swizzle) { b = id & 7; rest = id >> 3; }
    else             { b = id / (N * BINS); rest = id % (N * BINS); }
    const int n  = rest / BINS;
    const int hw = rest % BINS;
    const int w  = hw % PW;           // x-bin
    const int h  = hw / PW;           // y-bin

    const int4 roi = *reinterpret_cast<const int4*>(&rois[(b * N + n) * 4]);
    const int minX = roi.x, minY = roi.y, maxX = roi.z, maxY = roi.w;
    const int dx = (maxX - minX) / PW;   // >= 2
    const int dy = (maxY - minY) / PH;   // >= 2

    // Bin k covers [lo+k*d, lo+(k+1)*d); last bin extends to hi.
    const int xs = minX + w * dx;
    const int xe = (w == PW - 1) ? maxX : (xs + dx);
    const int ys = minY + h * dy;
    const int ye = (h == PH - 1) ? maxY : (ys + dy);

    const int wv = threadIdx.x >> 6;  // wave 0/1
    const int t  = threadIdx.x & 63;
    const int pp = t >> 5;            // row-in-pair (0/1)
    const int c0 = (t & 31) * 4;      // 4 channels per lane

    const int H   = ye - ys;          // wave-uniform, >= 2
    const int P   = H >> 1;           // pair-loads per column, >= 1
    const int odd = H & 1;

    const int colStride = Y * C;      // floats per x-column (16384)
    const float* base = feat + (b << 21) + c0;

    float4 m; m.x = m.y = m.z = m.w = -INFINITY;

    int xi = xs + wv;                 // this wave's columns: stride 2
    // Paired owned columns (xi, xi+2): 2 cols x 2 pairs = 4 loads in flight.
    for (; xi + 2 < xe; xi += 4) {
        const float* p0 = base + (xi * Y + ys + pp) * C;
        const float* p1 = p0 + 2 * colStride;
        int k = P;
        for (; k >= 2; k -= 2) {
            const float4 v0 = *reinterpret_cast<const float4*>(p0);
            const float4 v1 = *reinterpret_cast<const float4*>(p0 + 2 * C);
            const float4 v2 = *reinterpret_cast<const float4*>(p1);
            const float4 v3 = *reinterpret_cast<const float4*>(p1 + 2 * C);
            p0 += 4 * C; p1 += 4 * C;
            m = max4(m, max4(max4(v0, v1), max4(v2, v3)));
        }
        if (k) {   // uniform remainder pair (one per column)
            const float4 v0 = *reinterpret_cast<const float4*>(p0);
            const float4 v1 = *reinterpret_cast<const float4*>(p1);
            m = max4(m, max4(v0, v1));
        }
        if (odd) { // last row: same-address 512B broadcast per column
            const float* q0 = base + (xi * Y + (ye - 1)) * C;
            const float4 v0 = *reinterpret_cast<const float4*>(q0);
            const float4 v1 = *reinterpret_cast<const float4*>(q0 + 2 * colStride);
            m = max4(m, max4(v0, v1));
        }
    }
    if (xi < xe) {  // solo leftover column for this wave
        const float* p0 = base + (xi * Y + ys + pp) * C;
        int k = P;
        for (; k >= 2; k -= 2) {
            const float4 v0 = *reinterpret_cast<const float4*>(p0);
            const float4 v1 = *reinterpret_cast<const float4*>(p0 + 2 * C);
            p0 += 4 * C;
            m = max4(m, max4(v0, v1));
        }
        if (k) {
            const float4 v0 = *reinterpret_cast<const float4*>(p0);
            m = max4(m, v0);
        }
        if (odd) {
            const float4 v0 = *reinterpret_cast<const float4*>(base + (xi * Y + (ye - 1)) * C);
            m = max4(m, v0);
        }
    }

    // Merge the two row-parity halves (lane t <-> t^32 hold the same channels).
    m.x = fmaxf(m.x, __shfl_xor(m.x, 32));
    m.y = fmaxf(m.y, __shfl_xor(m.y, 32));
    m.z = fmaxf(m.z, __shfl_xor(m.z, 32));
    m.w = fmaxf(m.w, __shfl_xor(m.w, 32));

    // Cross-wave merge (1KB LDS, one barrier). No early returns before this.
    __shared__ float4 buf[2][32];
    if (t < 32) buf[wv][t & 31] = m;
    __syncthreads();
    if (wv == 0 && t < 32) {
        m = max4(m, buf[1][t & 31]);
        const int oidx = (((b * N + n) * PH + h) * PW + w) * C + c0;
        *reinterpret_cast<float4*>(&out[oidx]) = m;
    }
}

extern "C" void kernel_launch(void* const* d_in, const int* in_sizes, int n_in,
                              void* d_out, int out_size, void* d_ws, size_t ws_size,
                              hipStream_t stream) {
    const float* feat = (const float*)d_in[0];
    const int*   rois = (const int*)d_in[1];
    float*       out  = (float*)d_out;

    // Shapes per setup_inputs(): B=8, X=Y=C=128, N=128.
    const int X = 128, Y = 128, C = 128;
    const int B = in_sizes[0] / (X * Y * C);
    const int N = in_sizes[1] / (4 * B);

    const int swz = (B == 8) ? 1 : 0;
    dim3 grid(B * N * BINS);
    roi_maxpool_kernel<<<grid, 128, 0, stream>>>(feat, rois, out, N, swz);
}